// Round 6
// baseline (190.471 us; speedup 1.0000x reference)
//
#include <hip/hip_runtime.h>

#define BB 16
#define NN 2048
#define DIN 160
#define IS 32
#define NCAT 64
#define EMBD 64
#define NCTX 2047
#define SS 66               // LDS row stride (floats) for xs[96][SS]
#define TPB_COLS 64         // columns per block
#define NTILE 32            // tiles per batch
#define GRID1 (BB * NTILE)  // 512

// ---------------------------------------------------------------------------
// K1: partial G = xq.xq^T (32x32), K = xcat.xq^T (64x32) per 64-col tile.
// Block 256 = 4 waves; wave mg handles 16 m's; thread (i4,d4) owns a
// 4x4 G-tile (rows i0..i0+3) and 8x4 K-tile (rows i4+8j). Partials reduced
// across the 4 waves in LDS, stored to Pg/Pk. Last block per batch (atomic
// counter) reduces 32 partials and runs the tiny per-batch matrix chain:
//   C0 = emb.K;  l=0..2: W += s*diag(a_l)*C;  C += M.(s*diag(a_l)*C.G) (l<2)
//   U = emb^T.W -> Ubuf[b]
// ---------------------------------------------------------------------------
__global__ __launch_bounds__(256) void k_gram_chain(
    const float* __restrict__ x, const float* __restrict__ alpha,
    const float* __restrict__ kp, const float* __restrict__ emb,
    const float* __restrict__ Mm,
    float* __restrict__ Pg, float* __restrict__ Pk,
    float* __restrict__ Ubuf, int* __restrict__ cnt)
{
    __shared__ float xs[96 * SS];     // 25,344 B  [r][m] row-major
    __shared__ float cbuf[10368];     // 41,472 B  reduce scratch / chain arrays

    const int t = threadIdx.x;
    const int blk = blockIdx.x;
    const int b = blk >> 5;
    const int tile = blk & 31;
    const int n0 = tile << 6;
    const float* xb = x + (size_t)b * DIN * NN;

    // ---- stage rows 0..95 x 64 cols, row-major (b64 writes, conflict-free) ----
    for (int idx = t; idx < 96 * 32; idx += 256) {
        const int r = idx >> 5;
        const int mc = (idx & 31) << 1;
        *(float2*)&xs[r * SS + mc] = *(const float2*)&xb[r * NN + n0 + mc];
    }
    __syncthreads();
    if (tile == 31 && t < 96) xs[t * SS + 63] = 0.f;  // exclude global col 2047
    if (tile == 31) __syncthreads();

    // ---- register-tiled partial accumulation ----
    const int mg = t >> 6;          // wave id 0..3 -> m range
    const int lane = t & 63;
    const int i4 = lane >> 3;       // 0..7
    const int d4 = lane & 7;        // 0..7
    const int i0 = i4 << 2;
    const int d0 = d4 << 2;
    const int m0 = mg << 4;

    float g[4][4], kk[8][4];
#pragma unroll
    for (int ii = 0; ii < 4; ii++)
#pragma unroll
        for (int jj = 0; jj < 4; jj++) g[ii][jj] = 0.f;
#pragma unroll
    for (int ii = 0; ii < 8; ii++)
#pragma unroll
        for (int jj = 0; jj < 4; jj++) kk[ii][jj] = 0.f;

    for (int m = m0; m < m0 + 16; m += 2) {
        float2 q[4], a[4], c[8];
#pragma unroll
        for (int j = 0; j < 4; j++) q[j] = *(const float2*)&xs[(d0 + j) * SS + m];
#pragma unroll
        for (int j = 0; j < 4; j++) a[j] = *(const float2*)&xs[(i0 + j) * SS + m];
#pragma unroll
        for (int j = 0; j < 8; j++) c[j] = *(const float2*)&xs[(32 + i4 + 8 * j) * SS + m];
#pragma unroll
        for (int ii = 0; ii < 4; ii++)
#pragma unroll
            for (int jj = 0; jj < 4; jj++)
                g[ii][jj] += a[ii].x * q[jj].x + a[ii].y * q[jj].y;
#pragma unroll
        for (int ii = 0; ii < 8; ii++)
#pragma unroll
            for (int jj = 0; jj < 4; jj++)
                kk[ii][jj] += c[ii].x * q[jj].x + c[ii].y * q[jj].y;
    }

    // ---- reduce 4 wave-partials via cbuf (stride 52 to spread banks) ----
    if (mg > 0) {
        float* p = cbuf + ((mg - 1) * 64 + lane) * 52;
#pragma unroll
        for (int ii = 0; ii < 4; ii++) *(float4*)&p[ii * 4] = *(float4*)&g[ii][0];
#pragma unroll
        for (int ii = 0; ii < 8; ii++) *(float4*)&p[16 + ii * 4] = *(float4*)&kk[ii][0];
    }
    __syncthreads();
    if (mg == 0) {
#pragma unroll
        for (int w = 0; w < 3; w++) {
            const float* p = cbuf + (w * 64 + lane) * 52;
#pragma unroll
            for (int ii = 0; ii < 4; ii++) {
                float4 v = *(const float4*)&p[ii * 4];
                g[ii][0] += v.x; g[ii][1] += v.y; g[ii][2] += v.z; g[ii][3] += v.w;
            }
#pragma unroll
            for (int ii = 0; ii < 8; ii++) {
                float4 v = *(const float4*)&p[16 + ii * 4];
                kk[ii][0] += v.x; kk[ii][1] += v.y; kk[ii][2] += v.z; kk[ii][3] += v.w;
            }
        }
        float* pg = Pg + (size_t)blk * 1024;
#pragma unroll
        for (int ii = 0; ii < 4; ii++) *(float4*)&pg[(i0 + ii) * 32 + d0] = *(float4*)&g[ii][0];
        float* pk = Pk + (size_t)blk * 2048;
#pragma unroll
        for (int ii = 0; ii < 8; ii++) *(float4*)&pk[(i4 + 8 * ii) * 32 + d0] = *(float4*)&kk[ii][0];
    }

    // ---- last block for this b runs the chain ----
    __shared__ int lastflag;
    __threadfence();
    __syncthreads();
    if (t == 0) lastflag = (atomicAdd(&cnt[b], 1) == NTILE - 1);
    __syncthreads();
    if (!lastflag) return;
    __threadfence();

    float (*G_s)[36] = (float(*)[36])cbuf;            // 32x36
    float (*K_s)[36] = (float(*)[36])(cbuf + 1152);   // 64x36
    float (*C_s)[36] = (float(*)[36])(cbuf + 3456);
    float (*W_s)[36] = (float(*)[36])(cbuf + 5760);
    float (*T_s)[36] = (float(*)[36])(cbuf + 8064);

    for (int idx = t; idx < 1024; idx += 256) {
        float s = 0.f;
#pragma unroll
        for (int gg = 0; gg < 32; gg++) s += Pg[((size_t)(b * 32 + gg)) * 1024 + idx];
        G_s[idx >> 5][idx & 31] = s;
    }
    for (int idx = t; idx < 2048; idx += 256) {
        float s = 0.f;
#pragma unroll
        for (int gg = 0; gg < 32; gg++) s += Pk[((size_t)(b * 32 + gg)) * 2048 + idx];
        K_s[idx >> 5][idx & 31] = s;
    }
    __syncthreads();

    const int r  = t >> 2;         // 0..63
    const int dd = (t & 3) << 3;   // 0,8,16,24

    // C0 = emb . K
    {
        const float* er = emb + r * EMBD;
        float acc[8];
#pragma unroll
        for (int j = 0; j < 8; j++) acc[j] = 0.f;
        for (int c = 0; c < 64; c++) {
            const float e = er[c];
#pragma unroll
            for (int j = 0; j < 8; j++) acc[j] += e * K_s[c][dd + j];
        }
#pragma unroll
        for (int j = 0; j < 8; j++) C_s[r][dd + j] = acc[j];
    }
    __syncthreads();

    const float scale = kp[0] * (1.f / (float)NCTX);
    for (int l = 0; l < 3; l++) {
        const float f = scale * alpha[l * EMBD + r];
#pragma unroll
        for (int j = 0; j < 8; j++) {
            const float w = f * C_s[r][dd + j];
            if (l == 0) W_s[r][dd + j] = w; else W_s[r][dd + j] += w;
        }
        if (l < 2) {
            float tacc[8];
#pragma unroll
            for (int j = 0; j < 8; j++) tacc[j] = 0.f;
            for (int d = 0; d < 32; d++) {
                const float cv = C_s[r][d];
#pragma unroll
                for (int j = 0; j < 8; j++) tacc[j] += cv * G_s[d][dd + j];
            }
#pragma unroll
            for (int j = 0; j < 8; j++) T_s[r][dd + j] = f * tacc[j];
            __syncthreads();
            const float* Mr = Mm + r * EMBD;
            float uacc[8];
#pragma unroll
            for (int j = 0; j < 8; j++) uacc[j] = 0.f;
            for (int jj = 0; jj < 64; jj++) {
                const float mv = Mr[jj];
#pragma unroll
                for (int j = 0; j < 8; j++) uacc[j] += mv * T_s[jj][dd + j];
            }
#pragma unroll
            for (int j = 0; j < 8; j++) C_s[r][dd + j] += uacc[j];
            __syncthreads();
        }
    }
    __syncthreads();

    // U[c][d] = sum_e emb[e][c] * W[e][d], c = r
    {
        float acc[8];
#pragma unroll
        for (int j = 0; j < 8; j++) acc[j] = 0.f;
        for (int e = 0; e < 64; e++) {
            const float ev = emb[e * EMBD + r];
#pragma unroll
            for (int j = 0; j < 8; j++) acc[j] += ev * W_s[e][dd + j];
        }
        float* Ur = Ubuf + (size_t)b * 2048 + r * 32 + dd;
#pragma unroll
        for (int j = 0; j < 8; j++) Ur[j] = acc[j];
    }
}

// ---------------------------------------------------------------------------
// K2: logits[:,n] = emb^T.x_tail[:,n] + U.xq[:,n]; softmax.
// Grid 256 = 16 b x 16 tiles; block 256: t = h*128+nl, h = c-half.
// ---------------------------------------------------------------------------
__global__ __launch_bounds__(256) void k_out(const float* __restrict__ x,
                                             const float* __restrict__ emb,
                                             const float* __restrict__ Ubuf,
                                             float* __restrict__ out) {
    __shared__ float lg_s[128][68];
    const int t = threadIdx.x;
    const int blk = blockIdx.x;
    const int b = blk >> 4;
    const int tile = blk & 15;
    const int h = t >> 7;
    const int nl = t & 127;
    const int n = (tile << 7) + nl;
    const int c0 = h << 5;
    const float* xb = x + (size_t)b * DIN * NN;

    float xq[IS];
#pragma unroll
    for (int d = 0; d < IS; d++) xq[d] = xb[d * NN + n];

    float lg[32];
    const float* Ub = Ubuf + (size_t)b * 2048;
#pragma unroll 4
    for (int cl = 0; cl < 32; cl++) {
        const float* Ur = Ub + (c0 + cl) * 32;  // wave-uniform -> s_load
        float s = 0.f;
#pragma unroll
        for (int k = 0; k < 8; k++) {
            float4 u = *(const float4*)&Ur[4 * k];
            s += u.x * xq[4*k] + u.y * xq[4*k+1] + u.z * xq[4*k+2] + u.w * xq[4*k+3];
        }
        lg[cl] = s;
    }
    for (int e = 0; e < 64; e++) {
        const float tv = xb[(IS + NCAT + e) * NN + n];
        const float* er = emb + e * EMBD + c0;  // wave-uniform
#pragma unroll
        for (int cl = 0; cl < 32; cl++) lg[cl] += er[cl] * tv;
    }

    const size_t base = ((size_t)b * NN + n) * (size_t)NCAT;
    float* lo = out + base + c0;
#pragma unroll
    for (int k = 0; k < 8; k++) {
        float4 v = {lg[4*k], lg[4*k+1], lg[4*k+2], lg[4*k+3]};
        *(float4*)&lo[4*k] = v;
        *(float4*)&lg_s[nl][c0 + 4*k] = v;
    }
    __syncthreads();

    const int o0 = (1 - h) << 5;
    float mx = lg[0];
#pragma unroll
    for (int cl = 1; cl < 32; cl++) mx = fmaxf(mx, lg[cl]);
    float og[32];
#pragma unroll
    for (int k = 0; k < 8; k++) {
        float4 v = *(const float4*)&lg_s[nl][o0 + 4*k];
        og[4*k] = v.x; og[4*k+1] = v.y; og[4*k+2] = v.z; og[4*k+3] = v.w;
    }
#pragma unroll
    for (int cl = 0; cl < 32; cl++) mx = fmaxf(mx, og[cl]);

    float sum = 0.f;
#pragma unroll
    for (int cl = 0; cl < 32; cl++) {
        lg[cl] = __expf(lg[cl] - mx);
        sum += lg[cl];
    }
#pragma unroll
    for (int cl = 0; cl < 32; cl++) sum += __expf(og[cl] - mx);

    const float inv = 1.f / sum;
    float* po = out + (size_t)BB * NN * NCAT + base + c0;
#pragma unroll
    for (int k = 0; k < 8; k++) {
        float4 v = {lg[4*k]*inv, lg[4*k+1]*inv, lg[4*k+2]*inv, lg[4*k+3]*inv};
        *(float4*)&po[4*k] = v;
    }
}

extern "C" void kernel_launch(void* const* d_in, const int* in_sizes, int n_in,
                              void* d_out, int out_size, void* d_ws, size_t ws_size,
                              hipStream_t stream) {
    const float* x     = (const float*)d_in[0];
    const float* alpha = (const float*)d_in[1];
    const float* kp    = (const float*)d_in[2];
    const float* emb   = (const float*)d_in[3];
    const float* Mmat  = (const float*)d_in[4];
    float* out = (float*)d_out;

    float* Pg   = (float*)d_ws;                     // 512*1024
    float* Pk   = Pg + (size_t)GRID1 * 1024;        // 512*2048
    float* Ubuf = Pk + (size_t)GRID1 * 2048;        // 16*2048
    int*   cnt  = (int*)(Ubuf + (size_t)16 * 2048);

    hipMemsetAsync(cnt, 0, BB * sizeof(int), stream);
    k_gram_chain<<<GRID1, 256, 0, stream>>>(x, alpha, kp, emb, Mmat, Pg, Pk, Ubuf, cnt);
    k_out<<<256, 256, 0, stream>>>(x, emb, Ubuf, out);
}

// Round 7
// 147.322 us; speedup vs baseline: 1.2929x; 1.2929x over previous
//
#include <hip/hip_runtime.h>

#define BB 16
#define NN 2048
#define DIN 160
#define IS 32
#define NCAT 64
#define EMBD 64
#define NCTX 2047
#define SS 66               // LDS row stride (floats) for xs[96][SS]
#define NTILE 32            // 64-col tiles per batch
#define GRID1 (BB * NTILE)  // 512
#define NPART (NTILE * 4)   // per-wave partials per batch = 128

// ---------------------------------------------------------------------------
// K1: per-(tile,wave) partial G = xq.xq^T (32x32), K = xcat.xq^T (64x32).
// Block 256 = 4 waves; wave mg covers 16 m's; lane (i4,d4) owns a 4x4 G-tile
// and 8x4 K-tile. No fences, no atomics, no cross-wave reduce: each wave
// stores its own partial; K2 reduces 128/batch from L2.
// ---------------------------------------------------------------------------
__global__ __launch_bounds__(256) void k_gram(
    const float* __restrict__ x,
    float* __restrict__ Pg, float* __restrict__ Pk)
{
    __shared__ float xs[96 * SS];  // 25,344 B, [r][m] row-major
    const int t = threadIdx.x;
    const int blk = blockIdx.x;
    const int b = blk >> 5;
    const int tile = blk & 31;
    const int n0 = tile << 6;
    const float* xb = x + (size_t)b * DIN * NN;

    // stage rows 0..95 x 64 cols (coalesced float2; mask out global col 2047)
    for (int idx = t; idx < 96 * 32; idx += 256) {
        const int r = idx >> 5;
        const int mc = (idx & 31) << 1;
        float2 v = *(const float2*)&xb[r * NN + n0 + mc];
        if (n0 + mc + 1 == NCTX) v.y = 0.f;
        *(float2*)&xs[r * SS + mc] = v;
    }
    __syncthreads();

    const int mg = t >> 6;      // wave id -> m range
    const int lane = t & 63;
    const int i4 = lane >> 3;   // 0..7
    const int d4 = lane & 7;    // 0..7
    const int i0 = i4 << 2;
    const int d0 = d4 << 2;
    const int m0 = mg << 4;

    float g[4][4], kk[8][4];
#pragma unroll
    for (int ii = 0; ii < 4; ii++)
#pragma unroll
        for (int jj = 0; jj < 4; jj++) g[ii][jj] = 0.f;
#pragma unroll
    for (int ii = 0; ii < 8; ii++)
#pragma unroll
        for (int jj = 0; jj < 4; jj++) kk[ii][jj] = 0.f;

    for (int m = m0; m < m0 + 16; m += 2) {
        float2 q[4], a[4], c[8];
#pragma unroll
        for (int j = 0; j < 4; j++) q[j] = *(const float2*)&xs[(d0 + j) * SS + m];
#pragma unroll
        for (int j = 0; j < 4; j++) a[j] = *(const float2*)&xs[(i0 + j) * SS + m];
#pragma unroll
        for (int j = 0; j < 8; j++) c[j] = *(const float2*)&xs[(32 + i4 + 8 * j) * SS + m];
#pragma unroll
        for (int ii = 0; ii < 4; ii++)
#pragma unroll
            for (int jj = 0; jj < 4; jj++)
                g[ii][jj] += a[ii].x * q[jj].x + a[ii].y * q[jj].y;
#pragma unroll
        for (int ii = 0; ii < 8; ii++)
#pragma unroll
            for (int jj = 0; jj < 4; jj++)
                kk[ii][jj] += c[ii].x * q[jj].x + c[ii].y * q[jj].y;
    }

    const size_t slot = (size_t)blk * 4 + mg;
    float* pg = Pg + slot * 1024;
#pragma unroll
    for (int ii = 0; ii < 4; ii++)
        *(float4*)&pg[(i0 + ii) * 32 + d0] = *(float4*)&g[ii][0];
    float* pk = Pk + slot * 2048;
#pragma unroll
    for (int ii = 0; ii < 8; ii++)
        *(float4*)&pk[(i4 + 8 * ii) * 32 + d0] = *(float4*)&kk[ii][0];
}

// ---------------------------------------------------------------------------
// K2: per-batch: reduce 128 partials -> G (32x32), K (64x32); C0 = emb.K;
// l=0..2: W += s*diag(a_l)*C;  C += M.(s*diag(a_l)*C.G) (l<2); U = emb^T.W.
// Grid 16, block 256. Thread owns row r=t>>2, cols dd..dd+7.
// ---------------------------------------------------------------------------
__global__ __launch_bounds__(256) void k_chain(const float* __restrict__ Pg,
                                               const float* __restrict__ Pk,
                                               const float* __restrict__ alpha,
                                               const float* __restrict__ kp,
                                               const float* __restrict__ emb,
                                               const float* __restrict__ Mm,
                                               float* __restrict__ Ubuf) {
    __shared__ float G_s[32][36];
    __shared__ float K_s[64][36];
    __shared__ float C_s[64][36];
    __shared__ float W_s[64][36];
    __shared__ float T_s[64][36];
    const int t = threadIdx.x;
    const int b = blockIdx.x;

    // reduce G: thread owns float4 at idx4 = t*4
    {
        const int row = t >> 3, col = (t & 7) << 2;
        float4 s = {0, 0, 0, 0};
        const float* base = Pg + (size_t)b * NPART * 1024 + row * 32 + col;
#pragma unroll 8
        for (int p = 0; p < NPART; p++) {
            float4 v = *(const float4*)(base + (size_t)p * 1024);
            s.x += v.x; s.y += v.y; s.z += v.z; s.w += v.w;
        }
        *(float4*)&G_s[row][col] = s;
    }
    // reduce K: thread owns 2 float4s
    {
        const int row0 = t >> 2, col = (t & 3) << 3;
        const float* base = Pk + (size_t)b * NPART * 2048 + row0 * 32 + col;
        float4 s0 = {0, 0, 0, 0}, s1 = {0, 0, 0, 0};
#pragma unroll 8
        for (int p = 0; p < NPART; p++) {
            float4 v0 = *(const float4*)(base + (size_t)p * 2048);
            float4 v1 = *(const float4*)(base + (size_t)p * 2048 + 4);
            s0.x += v0.x; s0.y += v0.y; s0.z += v0.z; s0.w += v0.w;
            s1.x += v1.x; s1.y += v1.y; s1.z += v1.z; s1.w += v1.w;
        }
        *(float4*)&K_s[row0][col] = s0;
        *(float4*)&K_s[row0][col + 4] = s1;
    }
    __syncthreads();

    const int r  = t >> 2;         // 0..63
    const int dd = (t & 3) << 3;   // 0,8,16,24

    // C0 = emb . K
    {
        const float* er = emb + r * EMBD;
        float acc[8];
#pragma unroll
        for (int j = 0; j < 8; j++) acc[j] = 0.f;
        for (int c = 0; c < 64; c++) {
            const float e = er[c];
#pragma unroll
            for (int j = 0; j < 8; j++) acc[j] += e * K_s[c][dd + j];
        }
#pragma unroll
        for (int j = 0; j < 8; j++) C_s[r][dd + j] = acc[j];
    }
    __syncthreads();

    const float scale = kp[0] * (1.f / (float)NCTX);
    for (int l = 0; l < 3; l++) {
        const float f = scale * alpha[l * EMBD + r];
#pragma unroll
        for (int j = 0; j < 8; j++) {
            const float w = f * C_s[r][dd + j];
            if (l == 0) W_s[r][dd + j] = w; else W_s[r][dd + j] += w;
        }
        if (l < 2) {
            float tacc[8];
#pragma unroll
            for (int j = 0; j < 8; j++) tacc[j] = 0.f;
            for (int d = 0; d < 32; d++) {
                const float cv = C_s[r][d];
#pragma unroll
                for (int j = 0; j < 8; j++) tacc[j] += cv * G_s[d][dd + j];
            }
#pragma unroll
            for (int j = 0; j < 8; j++) T_s[r][dd + j] = f * tacc[j];
            __syncthreads();
            const float* Mr = Mm + r * EMBD;
            float uacc[8];
#pragma unroll
            for (int j = 0; j < 8; j++) uacc[j] = 0.f;
            for (int jj = 0; jj < 64; jj++) {
                const float mv = Mr[jj];
#pragma unroll
                for (int j = 0; j < 8; j++) uacc[j] += mv * T_s[jj][dd + j];
            }
#pragma unroll
            for (int j = 0; j < 8; j++) C_s[r][dd + j] += uacc[j];
            __syncthreads();
        }
    }
    __syncthreads();

    // U[c][d] = sum_e emb[e][c] * W[e][d], c = r
    {
        float acc[8];
#pragma unroll
        for (int j = 0; j < 8; j++) acc[j] = 0.f;
        for (int e = 0; e < 64; e++) {
            const float ev = emb[e * EMBD + r];
#pragma unroll
            for (int j = 0; j < 8; j++) acc[j] += ev * W_s[e][dd + j];
        }
        float* Ur = Ubuf + (size_t)b * 2048 + r * 32 + dd;
#pragma unroll
        for (int j = 0; j < 8; j++) Ur[j] = acc[j];
    }
}

// ---------------------------------------------------------------------------
// K3: logits[:,n] = emb^T.x_tail[:,n] + U.xq[:,n]; softmax.
// Grid 256 = 16 b x 16 tiles; block 256: t = h*128+nl, h = c-half.
// ---------------------------------------------------------------------------
__global__ __launch_bounds__(256) void k_out(const float* __restrict__ x,
                                             const float* __restrict__ emb,
                                             const float* __restrict__ Ubuf,
                                             float* __restrict__ out) {
    __shared__ float lg_s[128][68];
    const int t = threadIdx.x;
    const int blk = blockIdx.x;
    const int b = blk >> 4;
    const int tile = blk & 15;
    const int h = t >> 7;
    const int nl = t & 127;
    const int n = (tile << 7) + nl;
    const int c0 = h << 5;
    const float* xb = x + (size_t)b * DIN * NN;

    float xq[IS];
#pragma unroll
    for (int d = 0; d < IS; d++) xq[d] = xb[d * NN + n];

    float lg[32];
    const float* Ub = Ubuf + (size_t)b * 2048;
#pragma unroll 4
    for (int cl = 0; cl < 32; cl++) {
        const float* Ur = Ub + (c0 + cl) * 32;  // wave-uniform -> s_load
        float s = 0.f;
#pragma unroll
        for (int k = 0; k < 8; k++) {
            float4 u = *(const float4*)&Ur[4 * k];
            s += u.x * xq[4*k] + u.y * xq[4*k+1] + u.z * xq[4*k+2] + u.w * xq[4*k+3];
        }
        lg[cl] = s;
    }
    for (int e = 0; e < 64; e++) {
        const float tv = xb[(IS + NCAT + e) * NN + n];
        const float* er = emb + e * EMBD + c0;  // wave-uniform
#pragma unroll
        for (int cl = 0; cl < 32; cl++) lg[cl] += er[cl] * tv;
    }

    const size_t base = ((size_t)b * NN + n) * (size_t)NCAT;
    float* lo = out + base + c0;
#pragma unroll
    for (int k = 0; k < 8; k++) {
        float4 v = {lg[4*k], lg[4*k+1], lg[4*k+2], lg[4*k+3]};
        *(float4*)&lo[4*k] = v;
        *(float4*)&lg_s[nl][c0 + 4*k] = v;
    }
    __syncthreads();

    const int o0 = (1 - h) << 5;
    float mx = lg[0];
#pragma unroll
    for (int cl = 1; cl < 32; cl++) mx = fmaxf(mx, lg[cl]);
    float og[32];
#pragma unroll
    for (int k = 0; k < 8; k++) {
        float4 v = *(const float4*)&lg_s[nl][o0 + 4*k];
        og[4*k] = v.x; og[4*k+1] = v.y; og[4*k+2] = v.z; og[4*k+3] = v.w;
    }
#pragma unroll
    for (int cl = 0; cl < 32; cl++) mx = fmaxf(mx, og[cl]);

    float sum = 0.f;
#pragma unroll
    for (int cl = 0; cl < 32; cl++) {
        lg[cl] = __expf(lg[cl] - mx);
        sum += lg[cl];
    }
#pragma unroll
    for (int cl = 0; cl < 32; cl++) sum += __expf(og[cl] - mx);

    const float inv = 1.f / sum;
    float* po = out + (size_t)BB * NN * NCAT + base + c0;
#pragma unroll
    for (int k = 0; k < 8; k++) {
        float4 v = {lg[4*k]*inv, lg[4*k+1]*inv, lg[4*k+2]*inv, lg[4*k+3]*inv};
        *(float4*)&po[4*k] = v;
    }
}

extern "C" void kernel_launch(void* const* d_in, const int* in_sizes, int n_in,
                              void* d_out, int out_size, void* d_ws, size_t ws_size,
                              hipStream_t stream) {
    const float* x     = (const float*)d_in[0];
    const float* alpha = (const float*)d_in[1];
    const float* kp    = (const float*)d_in[2];
    const float* emb   = (const float*)d_in[3];
    const float* Mmat  = (const float*)d_in[4];
    float* out = (float*)d_out;

    float* Pg   = (float*)d_ws;                         // 2048 * 1024 floats
    float* Pk   = Pg + (size_t)GRID1 * 4 * 1024;        // 2048 * 2048 floats
    float* Ubuf = Pk + (size_t)GRID1 * 4 * 2048;        // 16 * 2048 floats

    k_gram <<<GRID1, 256, 0, stream>>>(x, Pg, Pk);
    k_chain<<<BB,    256, 0, stream>>>(Pg, Pk, alpha, kp, emb, Mmat, Ubuf);
    k_out  <<<256,   256, 0, stream>>>(x, emb, Ubuf, out);
}

// Round 8
// 125.936 us; speedup vs baseline: 1.5124x; 1.1698x over previous
//
#include <hip/hip_runtime.h>

#define BB 16
#define NN 2048
#define DIN 160
#define IS 32
#define NCAT 64
#define EMBD 64
#define NCTX 2047
#define SS 66               // LDS row stride (floats) for xs[96][SS]
#define NTILE 32            // 64-col tiles per batch
#define GRID1 (BB * NTILE)  // 512
#define NPART NTILE         // partials per batch (after in-block reduce)

// ---------------------------------------------------------------------------
// K1: per-tile partial G = xq.xq^T (32x32), K = xcat.xq^T (64x32).
// Block 256 = 4 waves; wave mg covers 16 m's; lane (i4,d4) owns a 4x4 G-tile
// and 8x4 K-tile. Cross-wave LDS reduce (no fences/atomics) -> one partial
// per block, 32 per batch.
// ---------------------------------------------------------------------------
__global__ __launch_bounds__(256) void k_gram(
    const float* __restrict__ x,
    float* __restrict__ Pg, float* __restrict__ Pk)
{
    __shared__ float xs[96 * SS];  // 25,344 B, [r][m] row-major
    __shared__ float cbuf[3 * 64 * 52];  // 39,936 B cross-wave reduce scratch
    const int t = threadIdx.x;
    const int blk = blockIdx.x;
    const int b = blk >> 5;
    const int tile = blk & 31;
    const int n0 = tile << 6;
    const float* xb = x + (size_t)b * DIN * NN;

    // stage rows 0..95 x 64 cols (coalesced float2; mask out global col 2047)
    for (int idx = t; idx < 96 * 32; idx += 256) {
        const int r = idx >> 5;
        const int mc = (idx & 31) << 1;
        float2 v = *(const float2*)&xb[r * NN + n0 + mc];
        if (n0 + mc + 1 == NCTX) v.y = 0.f;
        *(float2*)&xs[r * SS + mc] = v;
    }
    __syncthreads();

    const int mg = t >> 6;      // wave id -> m range
    const int lane = t & 63;
    const int i4 = lane >> 3;   // 0..7
    const int d4 = lane & 7;    // 0..7
    const int i0 = i4 << 2;
    const int d0 = d4 << 2;
    const int m0 = mg << 4;

    float g[4][4], kk[8][4];
#pragma unroll
    for (int ii = 0; ii < 4; ii++)
#pragma unroll
        for (int jj = 0; jj < 4; jj++) g[ii][jj] = 0.f;
#pragma unroll
    for (int ii = 0; ii < 8; ii++)
#pragma unroll
        for (int jj = 0; jj < 4; jj++) kk[ii][jj] = 0.f;

    for (int m = m0; m < m0 + 16; m += 2) {
        float2 q[4], a[4], c[8];
#pragma unroll
        for (int j = 0; j < 4; j++) q[j] = *(const float2*)&xs[(d0 + j) * SS + m];
#pragma unroll
        for (int j = 0; j < 4; j++) a[j] = *(const float2*)&xs[(i0 + j) * SS + m];
#pragma unroll
        for (int j = 0; j < 8; j++) c[j] = *(const float2*)&xs[(32 + i4 + 8 * j) * SS + m];
#pragma unroll
        for (int ii = 0; ii < 4; ii++)
#pragma unroll
            for (int jj = 0; jj < 4; jj++)
                g[ii][jj] += a[ii].x * q[jj].x + a[ii].y * q[jj].y;
#pragma unroll
        for (int ii = 0; ii < 8; ii++)
#pragma unroll
            for (int jj = 0; jj < 4; jj++)
                kk[ii][jj] += c[ii].x * q[jj].x + c[ii].y * q[jj].y;
    }

    // cross-wave reduce via cbuf (stride 52 spreads banks)
    if (mg > 0) {
        float* p = cbuf + ((mg - 1) * 64 + lane) * 52;
#pragma unroll
        for (int ii = 0; ii < 4; ii++) *(float4*)&p[ii * 4] = *(float4*)&g[ii][0];
#pragma unroll
        for (int ii = 0; ii < 8; ii++) *(float4*)&p[16 + ii * 4] = *(float4*)&kk[ii][0];
    }
    __syncthreads();
    if (mg == 0) {
#pragma unroll
        for (int w = 0; w < 3; w++) {
            const float* p = cbuf + (w * 64 + lane) * 52;
#pragma unroll
            for (int ii = 0; ii < 4; ii++) {
                float4 v = *(const float4*)&p[ii * 4];
                g[ii][0] += v.x; g[ii][1] += v.y; g[ii][2] += v.z; g[ii][3] += v.w;
            }
#pragma unroll
            for (int ii = 0; ii < 8; ii++) {
                float4 v = *(const float4*)&p[16 + ii * 4];
                kk[ii][0] += v.x; kk[ii][1] += v.y; kk[ii][2] += v.z; kk[ii][3] += v.w;
            }
        }
        float* pg = Pg + (size_t)blk * 1024;
#pragma unroll
        for (int ii = 0; ii < 4; ii++)
            *(float4*)&pg[(i0 + ii) * 32 + d0] = *(float4*)&g[ii][0];
        float* pk = Pk + (size_t)blk * 2048;
#pragma unroll
        for (int ii = 0; ii < 8; ii++)
            *(float4*)&pk[(i4 + 8 * ii) * 32 + d0] = *(float4*)&kk[ii][0];
    }
}

// ---------------------------------------------------------------------------
// K2: each block (b,tile of 128 cols) redundantly: reduce 32 partials ->
// G,K; chain -> U (in LDS); then logits[:,n] = emb^T.x_tail + U.xq; softmax.
// Grid 256 = 16 b x 16 tiles; block 256.
// ---------------------------------------------------------------------------
__global__ __launch_bounds__(256) void k_out(
    const float* __restrict__ x, const float* __restrict__ Pg,
    const float* __restrict__ Pk, const float* __restrict__ alpha,
    const float* __restrict__ kp, const float* __restrict__ emb,
    const float* __restrict__ Mm, float* __restrict__ out)
{
    __shared__ float G_s[32][36];
    __shared__ float K_s[64][36];
    __shared__ float C_s[64][36];
    __shared__ float W_s[64][36];
    __shared__ float U_s[64][36];
    __shared__ float lg_s[128][68];
    const int t = threadIdx.x;
    const int blk = blockIdx.x;
    const int b = blk >> 4;
    const int tile = blk & 15;
    const float* xb = x + (size_t)b * DIN * NN;

    // ---- reduce partials (L2-hot: 16 blocks/batch read the same 96 KB) ----
    {
        const int row = t >> 3, col = (t & 7) << 2;
        float4 s = {0, 0, 0, 0};
        const float* base = Pg + (size_t)b * NPART * 1024 + row * 32 + col;
#pragma unroll 8
        for (int p = 0; p < NPART; p++) {
            float4 v = *(const float4*)(base + (size_t)p * 1024);
            s.x += v.x; s.y += v.y; s.z += v.z; s.w += v.w;
        }
        *(float4*)&G_s[row][col] = s;
    }
    {
        const int row0 = t >> 2, col = (t & 3) << 3;
        const float* base = Pk + (size_t)b * NPART * 2048 + row0 * 32 + col;
        float4 s0 = {0, 0, 0, 0}, s1 = {0, 0, 0, 0};
#pragma unroll 8
        for (int p = 0; p < NPART; p++) {
            float4 v0 = *(const float4*)(base + (size_t)p * 2048);
            float4 v1 = *(const float4*)(base + (size_t)p * 2048 + 4);
            s0.x += v0.x; s0.y += v0.y; s0.z += v0.z; s0.w += v0.w;
            s1.x += v1.x; s1.y += v1.y; s1.z += v1.z; s1.w += v1.w;
        }
        *(float4*)&K_s[row0][col] = s0;
        *(float4*)&K_s[row0][col + 4] = s1;
    }
    __syncthreads();

    // ---- tiny chain: C0 = emb.K; l: W += f*C; C += M.(f*C.G) (l<2) ----
    const int r  = t >> 2;         // 0..63
    const int dd = (t & 3) << 3;   // 0,8,16,24
    {
        const float* er = emb + r * EMBD;
        float acc[8];
#pragma unroll
        for (int j = 0; j < 8; j++) acc[j] = 0.f;
        for (int c = 0; c < 64; c++) {
            const float e = er[c];
#pragma unroll
            for (int j = 0; j < 8; j++) acc[j] += e * K_s[c][dd + j];
        }
#pragma unroll
        for (int j = 0; j < 8; j++) C_s[r][dd + j] = acc[j];
    }
    __syncthreads();

    const float scale = kp[0] * (1.f / (float)NCTX);
    for (int l = 0; l < 3; l++) {
        const float f = scale * alpha[l * EMBD + r];
#pragma unroll
        for (int j = 0; j < 8; j++) {
            const float w = f * C_s[r][dd + j];
            if (l == 0) W_s[r][dd + j] = w; else W_s[r][dd + j] += w;
        }
        if (l < 2) {
            float tacc[8];
#pragma unroll
            for (int j = 0; j < 8; j++) tacc[j] = 0.f;
            for (int d = 0; d < 32; d++) {
                const float cv = C_s[r][d];
#pragma unroll
                for (int j = 0; j < 8; j++) tacc[j] += cv * G_s[d][dd + j];
            }
#pragma unroll
            for (int j = 0; j < 8; j++) U_s[r][dd + j] = f * tacc[j];  // U_s as T scratch
            __syncthreads();
            const float* Mr = Mm + r * EMBD;
            float uacc[8];
#pragma unroll
            for (int j = 0; j < 8; j++) uacc[j] = 0.f;
            for (int jj = 0; jj < 64; jj++) {
                const float mv = Mr[jj];
#pragma unroll
                for (int j = 0; j < 8; j++) uacc[j] += mv * U_s[jj][dd + j];
            }
#pragma unroll
            for (int j = 0; j < 8; j++) C_s[r][dd + j] += uacc[j];
            __syncthreads();
        }
    }
    __syncthreads();

    // U[c][d] = sum_e emb[e][c] * W[e][d]  (c = r) -> U_s
    {
        float acc[8];
#pragma unroll
        for (int j = 0; j < 8; j++) acc[j] = 0.f;
        for (int e = 0; e < 64; e++) {
            const float ev = emb[e * EMBD + r];
#pragma unroll
            for (int j = 0; j < 8; j++) acc[j] += ev * W_s[e][dd + j];
        }
#pragma unroll
        for (int j = 0; j < 8; j++) U_s[r][dd + j] = acc[j];
    }
    __syncthreads();

    // ---- epilogue: t = h*128 + nl ----
    const int h = t >> 7;
    const int nl = t & 127;
    const int n = (tile << 7) + nl;
    const int c0 = h << 5;

    float xq[IS];
#pragma unroll
    for (int d = 0; d < IS; d++) xq[d] = xb[d * NN + n];

    float lg[32];
#pragma unroll 4
    for (int cl = 0; cl < 32; cl++) {
        const float* Ur = &U_s[c0 + cl][0];  // wave-uniform LDS row -> broadcast
        float s = 0.f;
#pragma unroll
        for (int k = 0; k < 8; k++) {
            float4 u = *(const float4*)&Ur[4 * k];
            s += u.x * xq[4*k] + u.y * xq[4*k+1] + u.z * xq[4*k+2] + u.w * xq[4*k+3];
        }
        lg[cl] = s;
    }
    for (int e = 0; e < 64; e++) {
        const float tv = xb[(IS + NCAT + e) * NN + n];
        const float* er = emb + e * EMBD + c0;  // wave-uniform
#pragma unroll
        for (int cl = 0; cl < 32; cl++) lg[cl] += er[cl] * tv;
    }

    const size_t base = ((size_t)b * NN + n) * (size_t)NCAT;
    float* lo = out + base + c0;
#pragma unroll
    for (int k = 0; k < 8; k++) {
        float4 v = {lg[4*k], lg[4*k+1], lg[4*k+2], lg[4*k+3]};
        *(float4*)&lo[4*k] = v;
        *(float4*)&lg_s[nl][c0 + 4*k] = v;
    }
    __syncthreads();

    const int o0 = (1 - h) << 5;
    float mx = lg[0];
#pragma unroll
    for (int cl = 1; cl < 32; cl++) mx = fmaxf(mx, lg[cl]);
    float og[32];
#pragma unroll
    for (int k = 0; k < 8; k++) {
        float4 v = *(const float4*)&lg_s[nl][o0 + 4*k];
        og[4*k] = v.x; og[4*k+1] = v.y; og[4*k+2] = v.z; og[4*k+3] = v.w;
    }
#pragma unroll
    for (int cl = 0; cl < 32; cl++) mx = fmaxf(mx, og[cl]);

    float sum = 0.f;
#pragma unroll
    for (int cl = 0; cl < 32; cl++) {
        lg[cl] = __expf(lg[cl] - mx);
        sum += lg[cl];
    }
#pragma unroll
    for (int cl = 0; cl < 32; cl++) sum += __expf(og[cl] - mx);

    const float inv = 1.f / sum;
    float* po = out + (size_t)BB * NN * NCAT + base + c0;
#pragma unroll
    for (int k = 0; k < 8; k++) {
        float4 v = {lg[4*k]*inv, lg[4*k+1]*inv, lg[4*k+2]*inv, lg[4*k+3]*inv};
        *(float4*)&po[4*k] = v;
    }
}

extern "C" void kernel_launch(void* const* d_in, const int* in_sizes, int n_in,
                              void* d_out, int out_size, void* d_ws, size_t ws_size,
                              hipStream_t stream) {
    const float* x     = (const float*)d_in[0];
    const float* alpha = (const float*)d_in[1];
    const float* kp    = (const float*)d_in[2];
    const float* emb   = (const float*)d_in[3];
    const float* Mmat  = (const float*)d_in[4];
    float* out = (float*)d_out;

    float* Pg = (float*)d_ws;                 // 512 * 1024 floats
    float* Pk = Pg + (size_t)GRID1 * 1024;    // 512 * 2048 floats

    k_gram<<<GRID1, 256, 0, stream>>>(x, Pg, Pk);
    k_out <<<256,   256, 0, stream>>>(x, Pg, Pk, alpha, kp, emb, Mmat, out);
}